// Round 9
// baseline (69.748 us; speedup 1.0000x reference)
//
#include <hip/hip_runtime.h>
#include <math.h>

#define NPROP 4
#define SFULL 72
#define FH 11
#define FW 20
#define CB 512
#define FDIM 704   // CF*FH
#define HW 220     // FH*FW
#define CHT 32
#define NTILE 16   // CB/CHT
#define MROWS 160  // padded head-output rows (153 used)

typedef __attribute__((ext_vector_type(8))) short bf16x8;
typedef __attribute__((ext_vector_type(4))) float f32x4;

__device__ __forceinline__ unsigned short f2bf(float x) {
  unsigned u = __float_as_uint(x);
  u += 0x7FFFu + ((u >> 16) & 1u);
  return (unsigned short)(u >> 16);
}
// rounded bf16 in the TOP 16 bits
__device__ __forceinline__ unsigned bfbits(float x) {
  unsigned u = __float_as_uint(x);
  return u + 0x7FFFu + ((u >> 16) & 1u);
}

__device__ __forceinline__ void gload16(const void* g, void* l) {
  __builtin_amdgcn_global_load_lds(
      (const __attribute__((address_space(1))) void*)(g),
      (__attribute__((address_space(3))) void*)(l), 16, 0, 0);
}

// ---------------- k_prep: head-weight permute + conv_w B-frag layout ------
// blocks [0,160): Wc[m][f'] bf16 (f = c*11+y -> f' = y*64+c)
// blocks [160,224): Wb2[kg*512 + c*8 + i] = bf16(conv_w[c][kg*8+i])
__global__ void k_prep(const float* __restrict__ cls_w, const float* __restrict__ reg_w,
                       const float* __restrict__ att_w, const float* __restrict__ conv_w,
                       unsigned short* __restrict__ Wc, unsigned short* __restrict__ Wb2) {
  const int blk = blockIdx.x;
  const int t = threadIdx.x;
  if (blk < MROWS) {
    const int m = blk;
    const float* rowp = nullptr;
    if (m < 150) {
      int o = (m < 75) ? m : m - 75;
      int half = (m < 75) ? 0 : FDIM;
      rowp = ((o < 2) ? (cls_w + o * 2 * FDIM) : (reg_w + (o - 2) * 2 * FDIM)) + half;
    } else if (m < 153) {
      rowp = att_w + (m - 150) * FDIM;
    }
    for (int f = t; f < FDIM; f += 256) {
      float v = rowp ? rowp[f] : 0.0f;
      int fp = (f % FH) * 64 + (f / FH);
      Wc[m * FDIM + fp] = f2bf(v);
    }
  } else {
    const int kg = blk - MROWS;
    #pragma unroll
    for (int e0 = 0; e0 < 2; e0++) {
      int e = t + 256 * e0;
      Wb2[kg * 512 + e] = f2bf(conv_w[(e >> 3) * CB + kg * 8 + (e & 7)]);
    }
  }
}

// ---------------- Kernel 1: geometry + gathered 1x1 conv via MFMA ---------
// Pair-tile pipeline: depth-4 register ring (pf[4][4], vmcnt(8) steady),
// pack-once scatter of 2 K-tiles per phase, ONE barrier per 2 tiles
// (8 phases total), then both tiles' MFMAs. 2 blocks/CU (LDS ~80.6KB).
__global__ __launch_bounds__(512, 4) void k_gconv(
    const float* __restrict__ feat, const float* __restrict__ rpn,
    const unsigned short* __restrict__ Wb2, const float* __restrict__ conv_b,
    unsigned short* __restrict__ af, float* __restrict__ xs_full,
    float* __restrict__ out)
{
  __shared__ __align__(16) unsigned short W2[64 * 512];      // 64KB B-frags
  __shared__ __align__(16) unsigned short As[4 * 1760 + 160]; // 4 bufs + slack
  __shared__ float sh_sx[NPROP], sh_sy[NPROP], sh_it[NPROP];
  __shared__ int   sh_pos[48];
  __shared__ int   hcnt[55];
  __shared__ unsigned hword[55];

  const int b = blockIdx.x;
  const int t = threadIdx.x;
  const int l = t & 63;
  const int wid = t >> 6;
  const int nt = wid & 3;
  const int mhalf = wid >> 2;
  const int q = l >> 4, r = l & 15;

  // --- geometry ---
  if (t < NPROP) {
    const float* rp = rpn + (b * NPROP + t) * 4;
    float sx = rp[0] * (1.0f / 640.0f);
    float sy = rp[1] * (1.0f / 360.0f);
    float tn = tanf(rp[3] * 0.017453292519943295f);
    sh_sx[t] = sx; sh_sy[t] = sy; sh_it[t] = 1.0f / tn;
    out[(b * NPROP + t) * 77 + 2] = 1.0f - sy;
    out[(b * NPROP + t) * 77 + 3] = sx;
  }
  __syncthreads();
  if (t < NPROP * SFULL) {
    int p = t / SFULL, i = t - p * SFULL;
    float ay = 1.0f - (float)i * (1.0f / 71.0f);
    xs_full[(b * NPROP + p) * SFULL + i] =
        (sh_sx[p] + (sh_sy[p] - ay) * sh_it[p]) * 640.0f;
  }
  if (t < 48) {
    int ps = -1;
    if (t < NPROP * FH) {
      int p = t / FH, y = t - p * FH;
      float acy = 1.0f - (float)(10 - y) * 0.1f;
      float xc = (sh_sx[p] + (sh_sy[p] - acy) * sh_it[p]) * 640.0f;
      int ui = (int)rintf(xc * (1.0f / 32.0f));
      int cut = min(max(ui, 0), FW - 1);
      ps = ((ui < 0) | (ui > FW)) ? -1 : (t % FH) * FW + cut;
    }
    sh_pos[t] = ps;
  }
  __syncthreads();

  // --- hit lists per 4-float window j in [0,55): byte = s | (p&3)<<6 ---
  if (t < 55) {
    int cnt = 0; unsigned w = 0;
    for (int s = 0; s < 44; s++) {
      int p = sh_pos[s];
      if (p >= 0 && (p >> 2) == t) {
        w |= ((unsigned)(s | ((p & 3) << 6))) << (8 * cnt);
        cnt++;
      }
    }
    hcnt[t] = cnt; hword[t] = w;
  }
  __syncthreads();   // drains ALL prologue VMEM (vmcnt=0) before counted region

  // --- per-thread chunk descriptors (tile-invariant) ---
  int hn[4]; unsigned hwd[4]; int chS[4]; int cid[4];
  const int cbase = 220 * wid;
  #pragma unroll
  for (int k = 0; k < 4; k++) {
    int c = cbase + 64 * k + l;
    bool ok = (k < 3) || (l < 28);
    cid[k] = c;
    int j = c % 55;
    chS[k] = c / 55;
    hn[k]  = ok ? hcnt[j] : 0;
    hwd[k] = hword[j];
  }

  const float* fb = feat + (size_t)b * (CB * HW);

  // --- W2 staging: 8 gload16/thread (oldest in vm queue) ---
  #pragma unroll
  for (int k = 0; k < 8; k++) {
    int chunk = t + 512 * k;
    gload16(Wb2 + chunk * 8, (void*)&W2[chunk * 8]);
  }
  __builtin_amdgcn_sched_barrier(0);

  // --- feat tiles 0..3 into registers (depth-4 ring, 4 VMEM instrs each) ---
  float4 pf[4][4];
  #pragma unroll
  for (int s = 0; s < 4; s++) {
    const float4* g = (const float4*)(fb + s * (CHT * HW));
    #pragma unroll
    for (int k = 0; k < 3; k++) pf[s][k] = g[cid[k]];
    if (l < 28) pf[s][3] = g[cid[3]];
    __builtin_amdgcn_sched_barrier(0);
  }

  f32x4 acc0 = {0.f, 0.f, 0.f, 0.f}, acc1 = {0.f, 0.f, 0.f, 0.f};
  const int cW = 16 * nt + r;

#define SCATTER(ct) { \
    unsigned short* Asb = As + ((ct) & 3) * 1760; \
    _Pragma("unroll") \
    for (int k = 0; k < 4; k++) { \
      int n = hn[k]; \
      if (n) { \
        float4 v4 = pf[(ct) & 3][k]; \
        unsigned d0 = (bfbits(v4.x) >> 16) | (bfbits(v4.y) & 0xFFFF0000u); \
        unsigned d1 = (bfbits(v4.z) >> 16) | (bfbits(v4.w) & 0xFFFF0000u); \
        unsigned wd = hwd[k]; \
        _Pragma("unroll") \
        for (int h = 0; h < 4; h++) { \
          if (h < n) { \
            unsigned byte = (wd >> (8 * h)) & 255u; \
            unsigned s = byte & 63u; \
            unsigned sel = (byte & 128u) ? d1 : d0; \
            unsigned short val = (byte & 64u) ? (unsigned short)(sel >> 16) \
                                              : (unsigned short)sel; \
            Asb[s * 40 + chS[k]] = val; \
          } } } } }

#define ISSUE(ct) { \
    const float4* g = (const float4*)(fb + (ct) * (CHT * HW)); \
    _Pragma("unroll") \
    for (int k = 0; k < 3; k++) pf[(ct) & 3][k] = g[cid[k]]; \
    if (l < 28) pf[(ct) & 3][3] = g[cid[3]]; }

#define MFMA_STEP(pt) { \
    const unsigned short* Asp = As + ((pt) & 3) * 1760; \
    bf16x8 bw = *(const bf16x8*)&W2[(((pt) * 4 + q) * 64 + cW) * 8]; \
    if (mhalf == 0) { \
      bf16x8 a0 = *(const bf16x8*)&Asp[(0 + r) * 40 + q * 8]; \
      bf16x8 a1 = *(const bf16x8*)&Asp[(16 + r) * 40 + q * 8]; \
      asm volatile("s_waitcnt lgkmcnt(0)" ::: "memory"); \
      __builtin_amdgcn_sched_barrier(0); \
      acc0 = __builtin_amdgcn_mfma_f32_16x16x32_bf16(a0, bw, acc0, 0, 0, 0); \
      acc1 = __builtin_amdgcn_mfma_f32_16x16x32_bf16(a1, bw, acc1, 0, 0, 0); \
    } else { \
      bf16x8 a2 = *(const bf16x8*)&Asp[(32 + r) * 40 + q * 8]; \
      asm volatile("s_waitcnt lgkmcnt(0)" ::: "memory"); \
      __builtin_amdgcn_sched_barrier(0); \
      acc0 = __builtin_amdgcn_mfma_f32_16x16x32_bf16(a2, bw, acc0, 0, 0, 0); \
    } }

  // 8 phases, 2 K-tiles each; ONE barrier per phase.
  #pragma unroll
  for (int pj = 0; pj < 8; pj++) {
    if (pj <= 6) { asm volatile("s_waitcnt vmcnt(8)" ::: "memory"); }
    else         { asm volatile("s_waitcnt vmcnt(0)" ::: "memory"); }
    __builtin_amdgcn_sched_barrier(0);

    SCATTER(2 * pj)
    SCATTER(2 * pj + 1)

    if (pj <= 5) {
      ISSUE(2 * pj + 4)
      ISSUE(2 * pj + 5)
    }
    asm volatile("s_waitcnt lgkmcnt(0)" ::: "memory");
    __builtin_amdgcn_sched_barrier(0);
    __builtin_amdgcn_s_barrier();          // pair (and at pj=0, W2) visible
    __builtin_amdgcn_sched_barrier(0);

    MFMA_STEP(2 * pj)
    MFMA_STEP(2 * pj + 1)
  }
#undef SCATTER
#undef ISSUE
#undef MFMA_STEP

  // epilogue: D[m=slot][c] -> af bf16 at (b*4+p)*704 + y*64 + c
  {
    const int c = cW;
    const int g = q;
    const float cb = conv_b[c];
    #pragma unroll
    for (int rr = 0; rr < 4; rr++) {
      if (mhalf == 0) {
        int m0 = g * 4 + rr;
        int p = m0 / FH, y = m0 - p * FH;
        float v = (sh_pos[m0] >= 0) ? (acc0[rr] + cb) : 0.0f;
        af[(size_t)(b * NPROP + p) * FDIM + y * 64 + c] = f2bf(v);
        int m1 = 16 + g * 4 + rr;
        p = m1 / FH; y = m1 - p * FH;
        v = (sh_pos[m1] >= 0) ? (acc1[rr] + cb) : 0.0f;
        af[(size_t)(b * NPROP + p) * FDIM + y * 64 + c] = f2bf(v);
      } else {
        int m2 = 32 + g * 4 + rr;
        if (m2 < 44) {
          int p = m2 / FH, y = m2 - p * FH;
          float v = (sh_pos[m2] >= 0) ? (acc0[rr] + cb) : 0.0f;
          af[(size_t)(b * NPROP + p) * FDIM + y * 64 + c] = f2bf(v);
        }
      }
    }
  }
}

// ---------------- Kernel 2: head GEMM (MFMA) + attention + assembly ------
__global__ __launch_bounds__(256) void k_head(
    const unsigned short* __restrict__ af, const float* __restrict__ xs,
    const unsigned short* __restrict__ Wc,
    const float* __restrict__ att_b, const float* __restrict__ cls_b,
    const float* __restrict__ reg_b, float* __restrict__ out)
{
  __shared__ __align__(16) unsigned short A_s[16 * 712];      // stride 712 bf16
  __shared__ __align__(16) unsigned short W_s[2][MROWS * 40]; // [n][k] stride 40
  __shared__ float Ys[16 * 161];
  __shared__ float Am[16][4];

  const int bg = blockIdx.x;
  const int t = threadIdx.x;
  const int l = t & 63;
  const int wid = t >> 6;

  {
    const unsigned* src = (const unsigned*)af + (size_t)bg * 16 * 352;
    for (int i = t; i < 16 * 352; i += 256) {
      int r = i / 352, ci = i - r * 352;
      ((unsigned*)A_s)[r * 356 + ci] = src[i];
    }
  }
  {
    #pragma unroll
    for (int e = t; e < 640; e += 256) {
      int n = e >> 2, jj = e & 3;
      uint4 ld = *(const uint4*)(Wc + n * FDIM + jj * 8);
      *(uint4*)(&W_s[0][n * 40 + jj * 8]) = ld;
    }
  }
  __syncthreads();

  f32x4 acc[3];
  acc[0] = (f32x4){0.f,0.f,0.f,0.f}; acc[1] = acc[0]; acc[2] = acc[0];

  for (int step = 0; step < 22; ++step) {
    int cur = step & 1;
    uint4 r0, r1, r2;
    bool h2 = (t + 512) < 640;
    if (step < 21) {
      int k0 = (step + 1) * 32;
      { int e = t;       int n = e >> 2, jj = e & 3; r0 = *(const uint4*)(Wc + n * FDIM + k0 + jj * 8); }
      { int e = t + 256; int n = e >> 2, jj = e & 3; r1 = *(const uint4*)(Wc + n * FDIM + k0 + jj * 8); }
      if (h2) { int e = t + 512; int n = e >> 2, jj = e & 3; r2 = *(const uint4*)(Wc + n * FDIM + k0 + jj * 8); }
    }
    bf16x8 a = *(const bf16x8*)(A_s + (l & 15) * 712 + step * 32 + (l >> 4) * 8);
    #pragma unroll
    for (int j = 0; j < 3; j++) {
      int ntl = wid + 4 * j;
      if (ntl < 10) {
        bf16x8 bb = *(const bf16x8*)(&W_s[cur][(ntl * 16 + (l & 15)) * 40 + (l >> 4) * 8]);
        acc[j] = __builtin_amdgcn_mfma_f32_16x16x32_bf16(a, bb, acc[j], 0, 0, 0);
      }
    }
    if (step < 21) {
      { int e = t;       int n = e >> 2, jj = e & 3; *(uint4*)(&W_s[cur ^ 1][n * 40 + jj * 8]) = r0; }
      { int e = t + 256; int n = e >> 2, jj = e & 3; *(uint4*)(&W_s[cur ^ 1][n * 40 + jj * 8]) = r1; }
      if (h2) { int e = t + 512; int n = e >> 2, jj = e & 3; *(uint4*)(&W_s[cur ^ 1][n * 40 + jj * 8]) = r2; }
    }
    __syncthreads();
  }

  #pragma unroll
  for (int j = 0; j < 3; j++) {
    int ntl = wid + 4 * j;
    if (ntl < 10) {
      #pragma unroll
      for (int r = 0; r < 4; r++)
        Ys[((l >> 4) * 4 + r) * 161 + ntl * 16 + (l & 15)] = acc[j][r];
    }
  }
  __syncthreads();

  if (t < 16) {
    float s0 = Ys[t * 161 + 150] + att_b[0];
    float s1 = Ys[t * 161 + 151] + att_b[1];
    float s2 = Ys[t * 161 + 152] + att_b[2];
    float mx = fmaxf(s0, fmaxf(s1, s2));
    float e0 = expf(s0 - mx), e1 = expf(s1 - mx), e2 = expf(s2 - mx);
    float inv = 1.0f / (e0 + e1 + e2);
    float aa[3] = {e0 * inv, e1 * inv, e2 * inv};
    int p = t & 3;
    #pragma unroll
    for (int qq = 0; qq < NPROP; qq++)
      Am[t][qq] = (qq == p) ? 0.0f : aa[(qq < p) ? qq : qq - 1];
  }
  __syncthreads();

  for (int d = t; d < 16 * 75; d += 256) {
    int row = d / 75, o = d - row * 75;
    float v = Ys[row * 161 + 75 + o];
    int base = row & ~3;
    #pragma unroll
    for (int qq = 0; qq < NPROP; qq++) v += Am[row][qq] * Ys[(base + qq) * 161 + o];
    v += (o < 2) ? cls_b[o] : reg_b[o - 2];
    int grow = bg * 16 + row;
    int col = (o < 2) ? o : o + 2;
    if (o >= 3) v += xs[grow * SFULL + (o - 3)];
    out[grow * 77 + col] = v;
  }
}

extern "C" void kernel_launch(void* const* d_in, const int* in_sizes, int n_in,
                              void* d_out, int out_size, void* d_ws, size_t ws_size,
                              hipStream_t stream) {
  const float* feat   = (const float*)d_in[0];
  const float* rpn    = (const float*)d_in[1];
  const float* conv_w = (const float*)d_in[2];
  const float* conv_b = (const float*)d_in[3];
  const float* att_w  = (const float*)d_in[4];
  const float* att_b  = (const float*)d_in[5];
  const float* cls_w  = (const float*)d_in[6];
  const float* cls_b  = (const float*)d_in[7];
  const float* reg_w  = (const float*)d_in[8];
  const float* reg_b  = (const float*)d_in[9];
  float* out = (float*)d_out;

  char* ws = (char*)d_ws;
  unsigned short* af  = (unsigned short*)ws;                        // 2,883,584 B
  float* xs           = (float*)(ws + 2883584);                     // 589,824 B
  unsigned short* Wc  = (unsigned short*)(ws + 2883584 + 589824);   // 225,280 B
  unsigned short* Wb2 = (unsigned short*)(ws + 2883584 + 589824 + 225280); // 65,536 B

  k_prep<<<224, 256, 0, stream>>>(cls_w, reg_w, att_w, conv_w, Wc, Wb2);
  k_gconv<<<512, 512, 0, stream>>>(feat, rpn, Wb2, conv_b, af, xs, out);
  k_head<<<128, 256, 0, stream>>>(af, xs, Wc, att_b, cls_b, reg_b, out);
}

// Round 10
// 67.592 us; speedup vs baseline: 1.0319x; 1.0319x over previous
//
#include <hip/hip_runtime.h>
#include <math.h>

#define NPROP 4
#define SFULL 72
#define FH 11
#define FW 20
#define CB 512
#define FDIM 704   // CF*FH
#define HW 220     // FH*FW
#define CHT 32
#define NTILE 16   // CB/CHT
#define MROWS 160  // padded head-output rows (153 used)

typedef __attribute__((ext_vector_type(8))) short bf16x8;
typedef __attribute__((ext_vector_type(4))) float f32x4;

__device__ __forceinline__ unsigned short f2bf(float x) {
  unsigned u = __float_as_uint(x);
  u += 0x7FFFu + ((u >> 16) & 1u);
  return (unsigned short)(u >> 16);
}
// rounded bf16 in the TOP 16 bits
__device__ __forceinline__ unsigned bfbits(float x) {
  unsigned u = __float_as_uint(x);
  return u + 0x7FFFu + ((u >> 16) & 1u);
}

__device__ __forceinline__ void gload16(const void* g, void* l) {
  __builtin_amdgcn_global_load_lds(
      (const __attribute__((address_space(1))) void*)(g),
      (__attribute__((address_space(3))) void*)(l), 16, 0, 0);
}

// ---------------- k_prep: head-weight permute + conv_w B-frag layout ------
// blocks [0,160): Wc[m][f'] bf16 (f = c*11+y -> f' = y*64+c)
// blocks [160,224): Wb2[kg*512 + c*8 + i] = bf16(conv_w[c][kg*8+i])
__global__ void k_prep(const float* __restrict__ cls_w, const float* __restrict__ reg_w,
                       const float* __restrict__ att_w, const float* __restrict__ conv_w,
                       unsigned short* __restrict__ Wc, unsigned short* __restrict__ Wb2) {
  const int blk = blockIdx.x;
  const int t = threadIdx.x;
  if (blk < MROWS) {
    const int m = blk;
    const float* rowp = nullptr;
    if (m < 150) {
      int o = (m < 75) ? m : m - 75;
      int half = (m < 75) ? 0 : FDIM;
      rowp = ((o < 2) ? (cls_w + o * 2 * FDIM) : (reg_w + (o - 2) * 2 * FDIM)) + half;
    } else if (m < 153) {
      rowp = att_w + (m - 150) * FDIM;
    }
    for (int f = t; f < FDIM; f += 256) {
      float v = rowp ? rowp[f] : 0.0f;
      int fp = (f % FH) * 64 + (f / FH);
      Wc[m * FDIM + fp] = f2bf(v);
    }
  } else {
    const int kg = blk - MROWS;
    #pragma unroll
    for (int e0 = 0; e0 < 2; e0++) {
      int e = t + 256 * e0;
      Wb2[kg * 512 + e] = f2bf(conv_w[(e >> 3) * CB + kg * 8 + (e & 7)]);
    }
  }
}

// ---------------- Kernel 1: geometry + gathered 1x1 conv via MFMA ---------
// Register-streamed feat (depth-3, vmcnt(8) steady), pack-once scatter of
// the 44 needed columns into a tiny bf16 A-buffer; ONE barrier per K-tile.
__global__ __launch_bounds__(512, 4) void k_gconv(
    const float* __restrict__ feat, const float* __restrict__ rpn,
    const unsigned short* __restrict__ Wb2, const float* __restrict__ conv_b,
    unsigned short* __restrict__ af, float* __restrict__ xs_full,
    float* __restrict__ out)
{
  __shared__ __align__(16) unsigned short W2[64 * 512];    // 64KB B-frags
  __shared__ __align__(16) unsigned short As[2 * 48 * 40]; // 7.5KB A dbuf
  __shared__ float sh_sx[NPROP], sh_sy[NPROP], sh_it[NPROP];
  __shared__ int   sh_pos[48];
  __shared__ int   hcnt[55];
  __shared__ unsigned hword[55];

  const int b = blockIdx.x;
  const int t = threadIdx.x;
  const int l = t & 63;
  const int wid = t >> 6;
  const int nt = wid & 3;
  const int mhalf = wid >> 2;
  const int q = l >> 4, r = l & 15;

  // --- geometry ---
  if (t < NPROP) {
    const float* rp = rpn + (b * NPROP + t) * 4;
    float sx = rp[0] * (1.0f / 640.0f);
    float sy = rp[1] * (1.0f / 360.0f);
    float tn = tanf(rp[3] * 0.017453292519943295f);
    sh_sx[t] = sx; sh_sy[t] = sy; sh_it[t] = 1.0f / tn;
    out[(b * NPROP + t) * 77 + 2] = 1.0f - sy;
    out[(b * NPROP + t) * 77 + 3] = sx;
  }
  __syncthreads();
  if (t < NPROP * SFULL) {
    int p = t / SFULL, i = t - p * SFULL;
    float ay = 1.0f - (float)i * (1.0f / 71.0f);
    xs_full[(b * NPROP + p) * SFULL + i] =
        (sh_sx[p] + (sh_sy[p] - ay) * sh_it[p]) * 640.0f;
  }
  if (t < 48) {
    int ps = -1;
    if (t < NPROP * FH) {
      int p = t / FH, y = t - p * FH;
      float acy = 1.0f - (float)(10 - y) * 0.1f;
      float xc = (sh_sx[p] + (sh_sy[p] - acy) * sh_it[p]) * 640.0f;
      int ui = (int)rintf(xc * (1.0f / 32.0f));
      int cut = min(max(ui, 0), FW - 1);
      ps = ((ui < 0) | (ui > FW)) ? -1 : (t % FH) * FW + cut;
    }
    sh_pos[t] = ps;
  }
  __syncthreads();

  // --- hit lists per 4-float window j in [0,55): byte = s | (p&3)<<6 ---
  if (t < 55) {
    int cnt = 0; unsigned w = 0;
    for (int s = 0; s < 44; s++) {
      int p = sh_pos[s];
      if (p >= 0 && (p >> 2) == t) {
        w |= ((unsigned)(s | ((p & 3) << 6))) << (8 * cnt);
        cnt++;
      }
    }
    hcnt[t] = cnt; hword[t] = w;
  }
  __syncthreads();

  // --- per-thread chunk descriptors (tile-invariant) ---
  // wave owns chunks [220*wid, 220*wid+220): lanes l, l+64, l+128, (l<28: l+192)
  int hn[4]; unsigned hwd[4]; int chS[4]; int cid[4];
  const int cbase = 220 * wid;
  #pragma unroll
  for (int k = 0; k < 4; k++) {
    int c = cbase + 64 * k + l;
    bool ok = (k < 3) || (l < 28);
    cid[k] = c;
    int j = c % 55;
    chS[k] = c / 55;
    hn[k]  = ok ? hcnt[j] : 0;
    hwd[k] = hword[j];
  }

  const float* fb = feat + (size_t)b * (CB * HW);

  // --- W2 staging: 8 gload16/thread (oldest in vm queue) ---
  #pragma unroll
  for (int k = 0; k < 8; k++) {
    int chunk = t + 512 * k;
    gload16(Wb2 + chunk * 8, (void*)&W2[chunk * 8]);
  }
  __builtin_amdgcn_sched_barrier(0);

  // --- feat tiles 0,1,2 into registers (depth-3, 4 VMEM instrs each) ---
  float4 pf[3][4];
  #pragma unroll
  for (int s = 0; s < 3; s++) {
    const float4* g = (const float4*)(fb + s * (CHT * HW));
    #pragma unroll
    for (int k = 0; k < 3; k++) pf[s][k] = g[cid[k]];
    if (l < 28) pf[s][3] = g[cid[3]];
    __builtin_amdgcn_sched_barrier(0);
  }

  f32x4 acc0 = {0.f, 0.f, 0.f, 0.f}, acc1 = {0.f, 0.f, 0.f, 0.f};
  const int cW = 16 * nt + r;

  #pragma unroll
  for (int ct = 0; ct < NTILE; ct++) {
    if (ct <= 13)      asm volatile("s_waitcnt vmcnt(8)" ::: "memory");
    else if (ct == 14) asm volatile("s_waitcnt vmcnt(4)" ::: "memory");
    else               asm volatile("s_waitcnt vmcnt(0)" ::: "memory");
    __builtin_amdgcn_sched_barrier(0);

    // scatter hits of tile ct -> As[ct&1]: pack chunk to bf16 once, extract
    unsigned short* Asb = As + (ct & 1) * 1920;
    #pragma unroll
    for (int k = 0; k < 4; k++) {
      int n = hn[k];
      if (n) {
        float4 v4 = pf[ct % 3][k];
        unsigned d0 = (bfbits(v4.x) >> 16) | (bfbits(v4.y) & 0xFFFF0000u);
        unsigned d1 = (bfbits(v4.z) >> 16) | (bfbits(v4.w) & 0xFFFF0000u);
        unsigned wd = hwd[k];
        #pragma unroll
        for (int h = 0; h < 4; h++) {
          if (h < n) {
            unsigned byte = (wd >> (8 * h)) & 255u;
            unsigned s = byte & 63u;
            unsigned sel = (byte & 128u) ? d1 : d0;
            unsigned short val = (byte & 64u) ? (unsigned short)(sel >> 16)
                                              : (unsigned short)sel;
            Asb[s * 40 + chS[k]] = val;
          }
        }
      }
    }
    // prefetch tile ct+3 into the register set just consumed
    if (ct + 3 < NTILE) {
      const float4* g = (const float4*)(fb + (ct + 3) * (CHT * HW));
      #pragma unroll
      for (int k = 0; k < 3; k++) pf[ct % 3][k] = g[cid[k]];
      if (l < 28) pf[ct % 3][3] = g[cid[3]];
    }
    asm volatile("s_waitcnt lgkmcnt(0)" ::: "memory");
    __builtin_amdgcn_sched_barrier(0);
    __builtin_amdgcn_s_barrier();          // A tile visible to all waves
    __builtin_amdgcn_sched_barrier(0);

    // fragments + MFMA
    bf16x8 bw = *(const bf16x8*)&W2[((ct * 4 + q) * 64 + cW) * 8];
    if (mhalf == 0) {
      bf16x8 a0 = *(const bf16x8*)&Asb[(0 + r) * 40 + q * 8];
      bf16x8 a1 = *(const bf16x8*)&Asb[(16 + r) * 40 + q * 8];
      asm volatile("s_waitcnt lgkmcnt(0)" ::: "memory");
      __builtin_amdgcn_sched_barrier(0);
      acc0 = __builtin_amdgcn_mfma_f32_16x16x32_bf16(a0, bw, acc0, 0, 0, 0);
      acc1 = __builtin_amdgcn_mfma_f32_16x16x32_bf16(a1, bw, acc1, 0, 0, 0);
    } else {
      bf16x8 a2 = *(const bf16x8*)&Asb[(32 + r) * 40 + q * 8];
      asm volatile("s_waitcnt lgkmcnt(0)" ::: "memory");
      __builtin_amdgcn_sched_barrier(0);
      acc0 = __builtin_amdgcn_mfma_f32_16x16x32_bf16(a2, bw, acc0, 0, 0, 0);
    }
  }

  // epilogue: D[m=slot][c] -> af bf16 at (b*4+p)*704 + y*64 + c
  {
    const int c = cW;
    const int g = q;
    const float cb = conv_b[c];
    #pragma unroll
    for (int rr = 0; rr < 4; rr++) {
      if (mhalf == 0) {
        int m0 = g * 4 + rr;
        int p = m0 / FH, y = m0 - p * FH;
        float v = (sh_pos[m0] >= 0) ? (acc0[rr] + cb) : 0.0f;
        af[(size_t)(b * NPROP + p) * FDIM + y * 64 + c] = f2bf(v);
        int m1 = 16 + g * 4 + rr;
        p = m1 / FH; y = m1 - p * FH;
        v = (sh_pos[m1] >= 0) ? (acc1[rr] + cb) : 0.0f;
        af[(size_t)(b * NPROP + p) * FDIM + y * 64 + c] = f2bf(v);
      } else {
        int m2 = 32 + g * 4 + rr;
        if (m2 < 44) {
          int p = m2 / FH, y = m2 - p * FH;
          float v = (sh_pos[m2] >= 0) ? (acc0[rr] + cb) : 0.0f;
          af[(size_t)(b * NPROP + p) * FDIM + y * 64 + c] = f2bf(v);
        }
      }
    }
  }
}

// ---------------- Kernel 2: head GEMM (MFMA) + attention + assembly ------
__global__ __launch_bounds__(256) void k_head(
    const unsigned short* __restrict__ af, const float* __restrict__ xs,
    const unsigned short* __restrict__ Wc,
    const float* __restrict__ att_b, const float* __restrict__ cls_b,
    const float* __restrict__ reg_b, float* __restrict__ out)
{
  __shared__ __align__(16) unsigned short A_s[16 * 712];      // stride 712 bf16
  __shared__ __align__(16) unsigned short W_s[2][MROWS * 40]; // [n][k] stride 40
  __shared__ float Ys[16 * 161];
  __shared__ float Am[16][4];

  const int bg = blockIdx.x;
  const int t = threadIdx.x;
  const int l = t & 63;
  const int wid = t >> 6;

  {
    const unsigned* src = (const unsigned*)af + (size_t)bg * 16 * 352;
    for (int i = t; i < 16 * 352; i += 256) {
      int r = i / 352, ci = i - r * 352;
      ((unsigned*)A_s)[r * 356 + ci] = src[i];
    }
  }
  {
    #pragma unroll
    for (int e = t; e < 640; e += 256) {
      int n = e >> 2, jj = e & 3;
      uint4 ld = *(const uint4*)(Wc + n * FDIM + jj * 8);
      *(uint4*)(&W_s[0][n * 40 + jj * 8]) = ld;
    }
  }
  __syncthreads();

  f32x4 acc[3];
  acc[0] = (f32x4){0.f,0.f,0.f,0.f}; acc[1] = acc[0]; acc[2] = acc[0];

  for (int step = 0; step < 22; ++step) {
    int cur = step & 1;
    uint4 r0, r1, r2;
    bool h2 = (t + 512) < 640;
    if (step < 21) {
      int k0 = (step + 1) * 32;
      { int e = t;       int n = e >> 2, jj = e & 3; r0 = *(const uint4*)(Wc + n * FDIM + k0 + jj * 8); }
      { int e = t + 256; int n = e >> 2, jj = e & 3; r1 = *(const uint4*)(Wc + n * FDIM + k0 + jj * 8); }
      if (h2) { int e = t + 512; int n = e >> 2, jj = e & 3; r2 = *(const uint4*)(Wc + n * FDIM + k0 + jj * 8); }
    }
    bf16x8 a = *(const bf16x8*)(A_s + (l & 15) * 712 + step * 32 + (l >> 4) * 8);
    #pragma unroll
    for (int j = 0; j < 3; j++) {
      int ntl = wid + 4 * j;
      if (ntl < 10) {
        bf16x8 bb = *(const bf16x8*)(&W_s[cur][(ntl * 16 + (l & 15)) * 40 + (l >> 4) * 8]);
        acc[j] = __builtin_amdgcn_mfma_f32_16x16x32_bf16(a, bb, acc[j], 0, 0, 0);
      }
    }
    if (step < 21) {
      { int e = t;       int n = e >> 2, jj = e & 3; *(uint4*)(&W_s[cur ^ 1][n * 40 + jj * 8]) = r0; }
      { int e = t + 256; int n = e >> 2, jj = e & 3; *(uint4*)(&W_s[cur ^ 1][n * 40 + jj * 8]) = r1; }
      if (h2) { int e = t + 512; int n = e >> 2, jj = e & 3; *(uint4*)(&W_s[cur ^ 1][n * 40 + jj * 8]) = r2; }
    }
    __syncthreads();
  }

  #pragma unroll
  for (int j = 0; j < 3; j++) {
    int ntl = wid + 4 * j;
    if (ntl < 10) {
      #pragma unroll
      for (int r = 0; r < 4; r++)
        Ys[((l >> 4) * 4 + r) * 161 + ntl * 16 + (l & 15)] = acc[j][r];
    }
  }
  __syncthreads();

  if (t < 16) {
    float s0 = Ys[t * 161 + 150] + att_b[0];
    float s1 = Ys[t * 161 + 151] + att_b[1];
    float s2 = Ys[t * 161 + 152] + att_b[2];
    float mx = fmaxf(s0, fmaxf(s1, s2));
    float e0 = expf(s0 - mx), e1 = expf(s1 - mx), e2 = expf(s2 - mx);
    float inv = 1.0f / (e0 + e1 + e2);
    float aa[3] = {e0 * inv, e1 * inv, e2 * inv};
    int p = t & 3;
    #pragma unroll
    for (int qq = 0; qq < NPROP; qq++)
      Am[t][qq] = (qq == p) ? 0.0f : aa[(qq < p) ? qq : qq - 1];
  }
  __syncthreads();

  for (int d = t; d < 16 * 75; d += 256) {
    int row = d / 75, o = d - row * 75;
    float v = Ys[row * 161 + 75 + o];
    int base = row & ~3;
    #pragma unroll
    for (int qq = 0; qq < NPROP; qq++) v += Am[row][qq] * Ys[(base + qq) * 161 + o];
    v += (o < 2) ? cls_b[o] : reg_b[o - 2];
    int grow = bg * 16 + row;
    int col = (o < 2) ? o : o + 2;
    if (o >= 3) v += xs[grow * SFULL + (o - 3)];
    out[grow * 77 + col] = v;
  }
}

extern "C" void kernel_launch(void* const* d_in, const int* in_sizes, int n_in,
                              void* d_out, int out_size, void* d_ws, size_t ws_size,
                              hipStream_t stream) {
  const float* feat   = (const float*)d_in[0];
  const float* rpn    = (const float*)d_in[1];
  const float* conv_w = (const float*)d_in[2];
  const float* conv_b = (const float*)d_in[3];
  const float* att_w  = (const float*)d_in[4];
  const float* att_b  = (const float*)d_in[5];
  const float* cls_w  = (const float*)d_in[6];
  const float* cls_b  = (const float*)d_in[7];
  const float* reg_w  = (const float*)d_in[8];
  const float* reg_b  = (const float*)d_in[9];
  float* out = (float*)d_out;

  char* ws = (char*)d_ws;
  unsigned short* af  = (unsigned short*)ws;                        // 2,883,584 B
  float* xs           = (float*)(ws + 2883584);                     // 589,824 B
  unsigned short* Wc  = (unsigned short*)(ws + 2883584 + 589824);   // 225,280 B
  unsigned short* Wb2 = (unsigned short*)(ws + 2883584 + 589824 + 225280); // 65,536 B

  k_prep<<<224, 256, 0, stream>>>(cls_w, reg_w, att_w, conv_w, Wc, Wb2);
  k_gconv<<<512, 512, 0, stream>>>(feat, rpn, Wb2, conv_b, af, xs, out);
  k_head<<<128, 256, 0, stream>>>(af, xs, Wc, att_b, cls_b, reg_b, out);
}